// Round 3
// baseline (474.360 us; speedup 1.0000x reference)
//
#include <hip/hip_runtime.h>

// Problem constants (from reference)
constexpr int NN = 50000;     // nodes
constexpr int NE = 400000;    // edges
constexpr int NV = 3;         // views
constexpr int DF = 128;       // per-view width
constexpr int F  = 384;       // total feature width (NV*DF)
constexpr int TR = 16;        // node rows per block tile (50000 = 16*3125 exactly)
constexpr int NB = (NN + 255) / 256;  // 196 scan blocks

static_assert(NN % TR == 0, "node tiling must be exact");

// ---------------- CSR build (by destination) ----------------

__global__ void k_count(const int* __restrict__ dst, int* __restrict__ deg) {
  int i = blockIdx.x * blockDim.x + threadIdx.x;
  int stride = gridDim.x * blockDim.x;
  for (int e = i; e < NE; e += stride) atomicAdd(&deg[dst[e]], 1);
}

__global__ void k_blocksum(const int* __restrict__ deg, int* __restrict__ bsum) {
  __shared__ int s[4];
  int i = blockIdx.x * 256 + threadIdx.x;
  int v = (i < NN) ? deg[i] : 0;
  for (int o = 32; o > 0; o >>= 1) v += __shfl_down(v, o);  // wave64 reduce
  if ((threadIdx.x & 63) == 0) s[threadIdx.x >> 6] = v;
  __syncthreads();
  if (threadIdx.x == 0) bsum[blockIdx.x] = s[0] + s[1] + s[2] + s[3];
}

__global__ void k_scanb(int* __restrict__ bsum, int nb, int* __restrict__ offs_n) {
  if (threadIdx.x == 0 && blockIdx.x == 0) {
    int run = 0;
    for (int i = 0; i < nb; ++i) { int v = bsum[i]; bsum[i] = run; run += v; }
    *offs_n = run;  // offs[NN] = NE
  }
}

__global__ void k_offsets(const int* __restrict__ deg, const int* __restrict__ bsum,
                          int* __restrict__ offs) {
  __shared__ int s[256];
  int t = threadIdx.x;
  int i = blockIdx.x * 256 + t;
  int v = (i < NN) ? deg[i] : 0;
  s[t] = v;
  __syncthreads();
  for (int o = 1; o < 256; o <<= 1) {     // Hillis-Steele inclusive scan
    int add = (t >= o) ? s[t - o] : 0;
    __syncthreads();
    s[t] += add;
    __syncthreads();
  }
  if (i < NN) offs[i] = bsum[blockIdx.x] + s[t] - v;  // exclusive
}

__global__ void k_scatter(const int* __restrict__ src, const int* __restrict__ dst,
                          const int* __restrict__ offs, int* __restrict__ cnt,
                          int* __restrict__ csr) {
  int i = blockIdx.x * blockDim.x + threadIdx.x;
  int stride = gridDim.x * blockDim.x;
  for (int e = i; e < NE; e += stride) {
    int d = dst[e];
    int pos = offs[d] + atomicAdd(&cnt[d], 1);
    csr[pos] = src[e];
  }
}

// ---------------- Fused aggregate + GEMM(+bias+ReLU) layer ----------------
// All 3 views in one block: per edge, one SGPR row base feeds 3 gathers at
// immediate offsets (+0 / +512B / +1024B) -> 12 loads in flight per 4-edge
// unroll, index logistics amortized 3x.

__device__ __forceinline__ float4 relu4(float4 a) {
  a.x = a.x > 0.f ? a.x : 0.f;
  a.y = a.y > 0.f ? a.y : 0.f;
  a.z = a.z > 0.f ? a.z : 0.f;
  a.w = a.w > 0.f ? a.w : 0.f;
  return a;
}

__global__ __launch_bounds__(256, 6)
void k_layer(const float* __restrict__ feat,
             const int* __restrict__ offs, const int* __restrict__ csr,
             const float* __restrict__ Wall, const float* __restrict__ ball,
             int wstride, int bstride, float* __restrict__ out) {
  __shared__ float sT[TR][F];      // 24 KB aggregated tile (all views)
  const int t = threadIdx.x;
  const int wave = t >> 6, lane = t & 63;
  const int row0 = blockIdx.x * TR;
  const int laneoff = lane * 2;    // col within view 0

  // Phase A: one wave per node-row, 4 rows per wave.
#pragma unroll
  for (int rr = 0; rr < TR / 4; ++rr) {
    const int r = wave * (TR / 4) + rr;
    const int node = row0 + r;
    float a0x = 0.f, a0y = 0.f, a1x = 0.f, a1y = 0.f, a2x = 0.f, a2y = 0.f;
    int e0 = offs[node], e1 = offs[node + 1];
    int e = e0;
    while (e < e1) {                    // wave-uniform loop
      int n = e1 - e; if (n > 64) n = 64;
      int ce = e + lane; if (ce > e1 - 1) ce = e1 - 1;   // clamped coalesced index load
      int idx = csr[ce];
      int j = 0;
      for (; j + 4 <= n; j += 4) {      // 4 edges x 3 views = 12 gathers in flight
        int s0 = __builtin_amdgcn_readlane(idx, j);
        int s1 = __builtin_amdgcn_readlane(idx, j + 1);
        int s2 = __builtin_amdgcn_readlane(idx, j + 2);
        int s3 = __builtin_amdgcn_readlane(idx, j + 3);
        const float* p0 = feat + (size_t)s0 * F + laneoff;
        const float* p1 = feat + (size_t)s1 * F + laneoff;
        const float* p2 = feat + (size_t)s2 * F + laneoff;
        const float* p3 = feat + (size_t)s3 * F + laneoff;
        float2 x00 = *(const float2*)(p0);
        float2 x01 = *(const float2*)(p0 + DF);
        float2 x02 = *(const float2*)(p0 + 2 * DF);
        float2 x10 = *(const float2*)(p1);
        float2 x11 = *(const float2*)(p1 + DF);
        float2 x12 = *(const float2*)(p1 + 2 * DF);
        float2 x20 = *(const float2*)(p2);
        float2 x21 = *(const float2*)(p2 + DF);
        float2 x22 = *(const float2*)(p2 + 2 * DF);
        float2 x30 = *(const float2*)(p3);
        float2 x31 = *(const float2*)(p3 + DF);
        float2 x32 = *(const float2*)(p3 + 2 * DF);
        a0x += x00.x; a0y += x00.y; a1x += x01.x; a1y += x01.y; a2x += x02.x; a2y += x02.y;
        a0x += x10.x; a0y += x10.y; a1x += x11.x; a1y += x11.y; a2x += x12.x; a2y += x12.y;
        a0x += x20.x; a0y += x20.y; a1x += x21.x; a1y += x21.y; a2x += x22.x; a2y += x22.y;
        a0x += x30.x; a0y += x30.y; a1x += x31.x; a1y += x31.y; a2x += x32.x; a2y += x32.y;
      }
      for (; j < n; ++j) {
        int s0 = __builtin_amdgcn_readlane(idx, j);
        const float* p0 = feat + (size_t)s0 * F + laneoff;
        float2 x00 = *(const float2*)(p0);
        float2 x01 = *(const float2*)(p0 + DF);
        float2 x02 = *(const float2*)(p0 + 2 * DF);
        a0x += x00.x; a0y += x00.y; a1x += x01.x; a1y += x01.y; a2x += x02.x; a2y += x02.y;
      }
      e += n;
    }
    *(float2*)&sT[r][laneoff]          = make_float2(a0x, a0y);
    *(float2*)&sT[r][DF + laneoff]     = make_float2(a1x, a1y);
    *(float2*)&sT[r][2 * DF + laneoff] = make_float2(a2x, a2y);
  }
  __syncthreads();

  // Phase B: per-view GEMM. Thread tile = 2 rows x 4 cols; W from global (L1/L2).
  const int cg = t & 31, rg = t >> 5;
  const int c = cg * 4;
#pragma unroll
  for (int v = 0; v < NV; ++v) {
    const float* __restrict__ W = Wall + (size_t)v * wstride;
    const float* __restrict__ bias = ball + (size_t)v * bstride;
    const float4* __restrict__ W4 = (const float4*)W;
    const float4 b4 = *(const float4*)(bias + c);
    float4 a0 = b4, a1 = b4;
#pragma unroll 8
    for (int d = 0; d < DF; ++d) {
      float4 w = W4[d * (DF / 4) + cg];
      float x0 = sT[rg * 2 + 0][v * DF + d];
      float x1 = sT[rg * 2 + 1][v * DF + d];
      a0.x = fmaf(x0, w.x, a0.x); a0.y = fmaf(x0, w.y, a0.y);
      a0.z = fmaf(x0, w.z, a0.z); a0.w = fmaf(x0, w.w, a0.w);
      a1.x = fmaf(x1, w.x, a1.x); a1.y = fmaf(x1, w.y, a1.y);
      a1.z = fmaf(x1, w.z, a1.z); a1.w = fmaf(x1, w.w, a1.w);
    }
    const int nodeb = row0 + rg * 2;
    *(float4*)(out + (size_t)(nodeb + 0) * F + v * DF + c) = relu4(a0);
    *(float4*)(out + (size_t)(nodeb + 1) * F + v * DF + c) = relu4(a1);
  }
}

// ---------------- launch ----------------

static inline size_t align_up(size_t x, size_t a) { return (x + a - 1) & ~(a - 1); }

extern "C" void kernel_launch(void* const* d_in, const int* in_sizes, int n_in,
                              void* d_out, int out_size, void* d_ws, size_t ws_size,
                              hipStream_t stream) {
  const float* h   = (const float*)d_in[0];
  const int*   src = (const int*)d_in[1];
  const int*   dst = (const int*)d_in[2];
  const float* W1  = (const float*)d_in[3];
  const float* b1  = (const float*)d_in[4];
  const float* W2  = (const float*)d_in[5];
  const float* b2  = (const float*)d_in[6];
  float* out = (float*)d_out;

  // Workspace layout
  char* ws = (char*)d_ws;
  size_t o = 0;
  int* deg  = (int*)(ws + o); o = align_up(o + (size_t)NN * 4, 1024);        // also reused as scatter cursor
  int* offs = (int*)(ws + o); o = align_up(o + (size_t)(NN + 1) * 4, 1024);
  int* bsum = (int*)(ws + o); o = align_up(o + 1024, 1024);
  int* csr  = (int*)(ws + o); o = align_up(o + (size_t)NE * 4, 1024);
  float* ybuf = (float*)(ws + o); o += (size_t)NN * F * 4;
  (void)ws_size; (void)n_in; (void)in_sizes; (void)out_size;

  // CSR build
  hipMemsetAsync(deg, 0, (size_t)NN * 4, stream);
  k_count<<<1024, 256, 0, stream>>>(dst, deg);
  k_blocksum<<<NB, 256, 0, stream>>>(deg, bsum);
  k_scanb<<<1, 64, 0, stream>>>(bsum, NB, offs + NN);
  k_offsets<<<NB, 256, 0, stream>>>(deg, bsum, offs);
  hipMemsetAsync(deg, 0, (size_t)NN * 4, stream);  // reuse as per-node cursor
  k_scatter<<<1024, 256, 0, stream>>>(src, dst, offs, deg, csr);

  // Two fused layers: layer1 per-view W1/b1, layer2 shared W2/b2
  const int grid = NN / TR;  // 3125
  k_layer<<<grid, 256, 0, stream>>>(h,    offs, csr, W1, b1, DF * DF, DF, ybuf);
  k_layer<<<grid, 256, 0, stream>>>(ybuf, offs, csr, W2, b2, 0,       0,  out);
}

// Round 4
// 356.807 us; speedup vs baseline: 1.3295x; 1.3295x over previous
//
#include <hip/hip_runtime.h>

// Problem constants (from reference)
constexpr int NN = 50000;     // nodes
constexpr int NE = 400000;    // edges
constexpr int NV = 3;         // views
constexpr int DF = 128;       // per-view width
constexpr int F  = 384;       // total feature width (NV*DF)
constexpr int TR = 32;        // node rows per block tile
constexpr int NB = (NN + 255) / 256;  // 196 scan blocks

// ---------------- CSR build (by destination) ----------------

__global__ void k_count(const int* __restrict__ dst, int* __restrict__ deg) {
  int i = blockIdx.x * blockDim.x + threadIdx.x;
  int stride = gridDim.x * blockDim.x;
  for (int e = i; e < NE; e += stride) atomicAdd(&deg[dst[e]], 1);
}

__global__ void k_blocksum(const int* __restrict__ deg, int* __restrict__ bsum) {
  __shared__ int s[4];
  int i = blockIdx.x * 256 + threadIdx.x;
  int v = (i < NN) ? deg[i] : 0;
  for (int o = 32; o > 0; o >>= 1) v += __shfl_down(v, o);  // wave64 reduce
  if ((threadIdx.x & 63) == 0) s[threadIdx.x >> 6] = v;
  __syncthreads();
  if (threadIdx.x == 0) bsum[blockIdx.x] = s[0] + s[1] + s[2] + s[3];
}

__global__ void k_scanb(int* __restrict__ bsum, int nb, int* __restrict__ offs_n) {
  if (threadIdx.x == 0 && blockIdx.x == 0) {
    int run = 0;
    for (int i = 0; i < nb; ++i) { int v = bsum[i]; bsum[i] = run; run += v; }
    *offs_n = run;  // offs[NN] = NE
  }
}

__global__ void k_offsets(const int* __restrict__ deg, const int* __restrict__ bsum,
                          int* __restrict__ offs) {
  __shared__ int s[256];
  int t = threadIdx.x;
  int i = blockIdx.x * 256 + t;
  int v = (i < NN) ? deg[i] : 0;
  s[t] = v;
  __syncthreads();
  for (int o = 1; o < 256; o <<= 1) {     // Hillis-Steele inclusive scan
    int add = (t >= o) ? s[t - o] : 0;
    __syncthreads();
    s[t] += add;
    __syncthreads();
  }
  if (i < NN) offs[i] = bsum[blockIdx.x] + s[t] - v;  // exclusive
}

__global__ void k_scatter(const int* __restrict__ src, const int* __restrict__ dst,
                          const int* __restrict__ offs, int* __restrict__ cnt,
                          int* __restrict__ csr) {
  int i = blockIdx.x * blockDim.x + threadIdx.x;
  int stride = gridDim.x * blockDim.x;
  for (int e = i; e < NE; e += stride) {
    int d = dst[e];
    int pos = offs[d] + atomicAdd(&cnt[d], 1);
    csr[pos] = src[e];
  }
}

// ---------------- Fused aggregate + GEMM(+bias+ReLU) layer ----------------
// out[n, v*DF + h] = relu( bias[h] + sum_d ( sum_{s->n} feat[s, v*DF + d] ) * W[d,h] )

__device__ __forceinline__ float4 relu4(float4 a) {
  a.x = a.x > 0.f ? a.x : 0.f;
  a.y = a.y > 0.f ? a.y : 0.f;
  a.z = a.z > 0.f ? a.z : 0.f;
  a.w = a.w > 0.f ? a.w : 0.f;
  return a;
}

__global__ __launch_bounds__(256, 4)
void k_layer(const float* __restrict__ feat,
             const int* __restrict__ offs, const int* __restrict__ csr,
             const float* __restrict__ Wall, const float* __restrict__ ball,
             int wstride, int bstride, float* __restrict__ out) {
  __shared__ float sT[TR][DF];     // 16 KB: aggregated tile
  const int t = threadIdx.x;
  const int v = blockIdx.y;
  const float* __restrict__ W = Wall + (size_t)v * wstride;
  const float* __restrict__ bias = ball + (size_t)v * bstride;

  // Phase A: aggregate. One wave per node-row; lane holds float2 (128 cols / 64 lanes).
  // Batch-load up to 64 edge indices coalesced, broadcast via readlane (SGPR base),
  // issue 8 independent 512B gathers per step -> deep memory pipeline.
  const int wave = t >> 6, lane = t & 63;
  const int row0 = blockIdx.x * TR;
  const int vcol = v * DF + lane * 2;

#pragma unroll
  for (int rr = 0; rr < TR / 4; ++rr) {
    int r = rr * 4 + wave;
    int node = row0 + r;
    float ax = 0.f, ay = 0.f;
    if (node < NN) {
      int e0 = offs[node], e1 = offs[node + 1];
      int e = e0;
      while (e < e1) {                    // wave-uniform loop
        int n = e1 - e; if (n > 64) n = 64;
        int ce = e + lane; if (ce > e1 - 1) ce = e1 - 1;   // clamped coalesced index load
        int idx = csr[ce];
        int j = 0;
        for (; j + 8 <= n; j += 8) {      // 8 independent gathers in flight
          int s0 = __builtin_amdgcn_readlane(idx, j);
          int s1 = __builtin_amdgcn_readlane(idx, j + 1);
          int s2 = __builtin_amdgcn_readlane(idx, j + 2);
          int s3 = __builtin_amdgcn_readlane(idx, j + 3);
          int s4 = __builtin_amdgcn_readlane(idx, j + 4);
          int s5 = __builtin_amdgcn_readlane(idx, j + 5);
          int s6 = __builtin_amdgcn_readlane(idx, j + 6);
          int s7 = __builtin_amdgcn_readlane(idx, j + 7);
          float2 x0 = *(const float2*)(feat + (size_t)s0 * F + vcol);
          float2 x1 = *(const float2*)(feat + (size_t)s1 * F + vcol);
          float2 x2 = *(const float2*)(feat + (size_t)s2 * F + vcol);
          float2 x3 = *(const float2*)(feat + (size_t)s3 * F + vcol);
          float2 x4 = *(const float2*)(feat + (size_t)s4 * F + vcol);
          float2 x5 = *(const float2*)(feat + (size_t)s5 * F + vcol);
          float2 x6 = *(const float2*)(feat + (size_t)s6 * F + vcol);
          float2 x7 = *(const float2*)(feat + (size_t)s7 * F + vcol);
          ax += x0.x; ay += x0.y;
          ax += x1.x; ay += x1.y;
          ax += x2.x; ay += x2.y;
          ax += x3.x; ay += x3.y;
          ax += x4.x; ay += x4.y;
          ax += x5.x; ay += x5.y;
          ax += x6.x; ay += x6.y;
          ax += x7.x; ay += x7.y;
        }
        if (j + 4 <= n) {                 // 4-wide step
          int s0 = __builtin_amdgcn_readlane(idx, j);
          int s1 = __builtin_amdgcn_readlane(idx, j + 1);
          int s2 = __builtin_amdgcn_readlane(idx, j + 2);
          int s3 = __builtin_amdgcn_readlane(idx, j + 3);
          float2 x0 = *(const float2*)(feat + (size_t)s0 * F + vcol);
          float2 x1 = *(const float2*)(feat + (size_t)s1 * F + vcol);
          float2 x2 = *(const float2*)(feat + (size_t)s2 * F + vcol);
          float2 x3 = *(const float2*)(feat + (size_t)s3 * F + vcol);
          ax += x0.x; ay += x0.y;
          ax += x1.x; ay += x1.y;
          ax += x2.x; ay += x2.y;
          ax += x3.x; ay += x3.y;
          j += 4;
        }
        for (; j < n; ++j) {
          int s0 = __builtin_amdgcn_readlane(idx, j);
          float2 x0 = *(const float2*)(feat + (size_t)s0 * F + vcol);
          ax += x0.x; ay += x0.y;
        }
        e += n;
      }
    }
    sT[r][lane * 2]     = ax;
    sT[r][lane * 2 + 1] = ay;
  }
  __syncthreads();

  // Phase B: GEMM. Thread tile = 4 rows x 4 cols. W read from global (L1/L2-resident,
  // wave-broadcast row access) -- no LDS stage, keeps occupancy high.
  const int cg = t & 31, rg = t >> 5;
  const int c = cg * 4;
  const float4 b4 = *(const float4*)(bias + c);
  float4 a0 = b4, a1 = b4, a2 = b4, a3 = b4;
  const float4* __restrict__ W4 = (const float4*)W;
#pragma unroll 8
  for (int d = 0; d < DF; ++d) {
    float4 w = W4[d * (DF / 4) + cg];
    float x0 = sT[rg * 4 + 0][d];
    float x1 = sT[rg * 4 + 1][d];
    float x2 = sT[rg * 4 + 2][d];
    float x3 = sT[rg * 4 + 3][d];
    a0.x = fmaf(x0, w.x, a0.x); a0.y = fmaf(x0, w.y, a0.y);
    a0.z = fmaf(x0, w.z, a0.z); a0.w = fmaf(x0, w.w, a0.w);
    a1.x = fmaf(x1, w.x, a1.x); a1.y = fmaf(x1, w.y, a1.y);
    a1.z = fmaf(x1, w.z, a1.z); a1.w = fmaf(x1, w.w, a1.w);
    a2.x = fmaf(x2, w.x, a2.x); a2.y = fmaf(x2, w.y, a2.y);
    a2.z = fmaf(x2, w.z, a2.z); a2.w = fmaf(x2, w.w, a2.w);
    a3.x = fmaf(x3, w.x, a3.x); a3.y = fmaf(x3, w.y, a3.y);
    a3.z = fmaf(x3, w.z, a3.z); a3.w = fmaf(x3, w.w, a3.w);
  }

  const int nodeb = row0 + rg * 4;
  if (nodeb + 0 < NN) *(float4*)(out + (size_t)(nodeb + 0) * F + v * DF + c) = relu4(a0);
  if (nodeb + 1 < NN) *(float4*)(out + (size_t)(nodeb + 1) * F + v * DF + c) = relu4(a1);
  if (nodeb + 2 < NN) *(float4*)(out + (size_t)(nodeb + 2) * F + v * DF + c) = relu4(a2);
  if (nodeb + 3 < NN) *(float4*)(out + (size_t)(nodeb + 3) * F + v * DF + c) = relu4(a3);
}

// ---------------- launch ----------------

static inline size_t align_up(size_t x, size_t a) { return (x + a - 1) & ~(a - 1); }

extern "C" void kernel_launch(void* const* d_in, const int* in_sizes, int n_in,
                              void* d_out, int out_size, void* d_ws, size_t ws_size,
                              hipStream_t stream) {
  const float* h   = (const float*)d_in[0];
  const int*   src = (const int*)d_in[1];
  const int*   dst = (const int*)d_in[2];
  const float* W1  = (const float*)d_in[3];
  const float* b1  = (const float*)d_in[4];
  const float* W2  = (const float*)d_in[5];
  const float* b2  = (const float*)d_in[6];
  float* out = (float*)d_out;

  // Workspace layout
  char* ws = (char*)d_ws;
  size_t o = 0;
  int* deg  = (int*)(ws + o); o = align_up(o + (size_t)NN * 4, 1024);        // also reused as scatter cursor
  int* offs = (int*)(ws + o); o = align_up(o + (size_t)(NN + 1) * 4, 1024);
  int* bsum = (int*)(ws + o); o = align_up(o + 1024, 1024);
  int* csr  = (int*)(ws + o); o = align_up(o + (size_t)NE * 4, 1024);
  float* ybuf = (float*)(ws + o); o += (size_t)NN * F * 4;
  (void)ws_size; (void)n_in; (void)in_sizes; (void)out_size;

  // CSR build
  hipMemsetAsync(deg, 0, (size_t)NN * 4, stream);
  k_count<<<1024, 256, 0, stream>>>(dst, deg);
  k_blocksum<<<NB, 256, 0, stream>>>(deg, bsum);
  k_scanb<<<1, 64, 0, stream>>>(bsum, NB, offs + NN);
  k_offsets<<<NB, 256, 0, stream>>>(deg, bsum, offs);
  hipMemsetAsync(deg, 0, (size_t)NN * 4, stream);  // reuse as per-node cursor
  k_scatter<<<1024, 256, 0, stream>>>(src, dst, offs, deg, csr);

  // Two fused layers: layer1 per-view W1/b1, layer2 shared W2/b2
  dim3 grid((NN + TR - 1) / TR, NV);
  k_layer<<<grid, 256, 0, stream>>>(h,    offs, csr, W1, b1, DF * DF, DF, ybuf);
  k_layer<<<grid, 256, 0, stream>>>(ybuf, offs, csr, W2, b2, 0,       0,  out);
}

// Round 5
// 311.481 us; speedup vs baseline: 1.5229x; 1.1455x over previous
//
#include <hip/hip_runtime.h>

// Problem constants (from reference)
constexpr int NN = 50000;     // nodes
constexpr int NE = 400000;    // edges
constexpr int NV = 3;         // views
constexpr int DF = 128;       // per-view width
constexpr int F  = 384;       // total feature width (NV*DF)
constexpr int TR = 32;        // node rows per block tile
constexpr int NB = (NN + 255) / 256;  // 196 scan blocks

// ---------------- CSR build (by destination) ----------------

__global__ void k_count(const int* __restrict__ dst, int* __restrict__ deg) {
  int i = blockIdx.x * blockDim.x + threadIdx.x;
  int stride = gridDim.x * blockDim.x;
  for (int e = i; e < NE; e += stride) atomicAdd(&deg[dst[e]], 1);
}

__global__ void k_blocksum(const int* __restrict__ deg, int* __restrict__ bsum) {
  __shared__ int s[4];
  int i = blockIdx.x * 256 + threadIdx.x;
  int v = (i < NN) ? deg[i] : 0;
  for (int o = 32; o > 0; o >>= 1) v += __shfl_down(v, o);  // wave64 reduce
  if ((threadIdx.x & 63) == 0) s[threadIdx.x >> 6] = v;
  __syncthreads();
  if (threadIdx.x == 0) bsum[blockIdx.x] = s[0] + s[1] + s[2] + s[3];
}

__global__ void k_scanb(int* __restrict__ bsum, int nb, int* __restrict__ offs_n) {
  if (threadIdx.x == 0 && blockIdx.x == 0) {
    int run = 0;
    for (int i = 0; i < nb; ++i) { int v = bsum[i]; bsum[i] = run; run += v; }
    *offs_n = run;  // offs[NN] = NE
  }
}

__global__ void k_offsets(const int* __restrict__ deg, const int* __restrict__ bsum,
                          int* __restrict__ offs) {
  __shared__ int s[256];
  int t = threadIdx.x;
  int i = blockIdx.x * 256 + t;
  int v = (i < NN) ? deg[i] : 0;
  s[t] = v;
  __syncthreads();
  for (int o = 1; o < 256; o <<= 1) {     // Hillis-Steele inclusive scan
    int add = (t >= o) ? s[t - o] : 0;
    __syncthreads();
    s[t] += add;
    __syncthreads();
  }
  if (i < NN) offs[i] = bsum[blockIdx.x] + s[t] - v;  // exclusive
}

__global__ void k_scatter(const int* __restrict__ src, const int* __restrict__ dst,
                          const int* __restrict__ offs, int* __restrict__ cnt,
                          int* __restrict__ csr) {
  int i = blockIdx.x * blockDim.x + threadIdx.x;
  int stride = gridDim.x * blockDim.x;
  for (int e = i; e < NE; e += stride) {
    int d = dst[e];
    int pos = offs[d] + atomicAdd(&cnt[d], 1);
    csr[pos] = src[e];
  }
}

// ---------------- fp32 -> bf16 (RNE) streaming conversion ----------------

__device__ __forceinline__ ushort f2bf(float f) {
  unsigned u = __float_as_uint(f);
  u = (u + 0x7fffu + ((u >> 16) & 1u)) >> 16;   // round-nearest-even
  return (ushort)u;
}

__global__ void k_tobf16(const float* __restrict__ in, ushort* __restrict__ outb, int n4) {
  int i = blockIdx.x * blockDim.x + threadIdx.x;
  int stride = gridDim.x * blockDim.x;
  const float4* in4 = (const float4*)in;
  for (int k = i; k < n4; k += stride) {
    float4 x = in4[k];
    ushort4 u;
    u.x = f2bf(x.x); u.y = f2bf(x.y); u.z = f2bf(x.z); u.w = f2bf(x.w);
    *(ushort4*)(outb + (size_t)k * 4) = u;
  }
}

// ---------------- Fused aggregate + GEMM(+bias+ReLU) layer ----------------
// Features stored bf16: per edge, lane loads one uint (2x bf16 = 4B); unpack is
// pure bit-ops (bf16->f32 == shift). Accumulate fp32 in LDS; GEMM fp32 VALU.

__device__ __forceinline__ float4 relu4(float4 a) {
  a.x = a.x > 0.f ? a.x : 0.f;
  a.y = a.y > 0.f ? a.y : 0.f;
  a.z = a.z > 0.f ? a.z : 0.f;
  a.w = a.w > 0.f ? a.w : 0.f;
  return a;
}

template <bool OUT_BF16>
__global__ __launch_bounds__(256, 4)
void k_layer(const ushort* __restrict__ feat,      // bf16 features [NN][F]
             const int* __restrict__ offs, const int* __restrict__ csr,
             const float* __restrict__ Wall, const float* __restrict__ ball,
             int wstride, int bstride, void* __restrict__ outp) {
  __shared__ float sT[TR][DF];     // 16 KB: aggregated tile (fp32)
  const int t = threadIdx.x;
  const int v = blockIdx.y;
  const float* __restrict__ W = Wall + (size_t)v * wstride;
  const float* __restrict__ bias = ball + (size_t)v * bstride;

  const int wave = t >> 6, lane = t & 63;
  const int row0 = blockIdx.x * TR;
  const int vcol = v * DF + lane * 2;   // element offset within row

#pragma unroll
  for (int rr = 0; rr < TR / 4; ++rr) {
    int r = rr * 4 + wave;
    int node = row0 + r;
    float ax = 0.f, ay = 0.f;
    if (node < NN) {
      int e0 = offs[node], e1 = offs[node + 1];
      int e = e0;
      while (e < e1) {                    // wave-uniform loop
        int n = e1 - e; if (n > 64) n = 64;
        int ce = e + lane; if (ce > e1 - 1) ce = e1 - 1;   // clamped coalesced index load
        int idx = csr[ce];
        int j = 0;
        for (; j + 8 <= n; j += 8) {      // 8 independent 4B gathers in flight
          int s0 = __builtin_amdgcn_readlane(idx, j);
          int s1 = __builtin_amdgcn_readlane(idx, j + 1);
          int s2 = __builtin_amdgcn_readlane(idx, j + 2);
          int s3 = __builtin_amdgcn_readlane(idx, j + 3);
          int s4 = __builtin_amdgcn_readlane(idx, j + 4);
          int s5 = __builtin_amdgcn_readlane(idx, j + 5);
          int s6 = __builtin_amdgcn_readlane(idx, j + 6);
          int s7 = __builtin_amdgcn_readlane(idx, j + 7);
          unsigned u0 = *(const unsigned*)(feat + (size_t)s0 * F + vcol);
          unsigned u1 = *(const unsigned*)(feat + (size_t)s1 * F + vcol);
          unsigned u2 = *(const unsigned*)(feat + (size_t)s2 * F + vcol);
          unsigned u3 = *(const unsigned*)(feat + (size_t)s3 * F + vcol);
          unsigned u4 = *(const unsigned*)(feat + (size_t)s4 * F + vcol);
          unsigned u5 = *(const unsigned*)(feat + (size_t)s5 * F + vcol);
          unsigned u6 = *(const unsigned*)(feat + (size_t)s6 * F + vcol);
          unsigned u7 = *(const unsigned*)(feat + (size_t)s7 * F + vcol);
          ax += __uint_as_float(u0 << 16); ay += __uint_as_float(u0 & 0xffff0000u);
          ax += __uint_as_float(u1 << 16); ay += __uint_as_float(u1 & 0xffff0000u);
          ax += __uint_as_float(u2 << 16); ay += __uint_as_float(u2 & 0xffff0000u);
          ax += __uint_as_float(u3 << 16); ay += __uint_as_float(u3 & 0xffff0000u);
          ax += __uint_as_float(u4 << 16); ay += __uint_as_float(u4 & 0xffff0000u);
          ax += __uint_as_float(u5 << 16); ay += __uint_as_float(u5 & 0xffff0000u);
          ax += __uint_as_float(u6 << 16); ay += __uint_as_float(u6 & 0xffff0000u);
          ax += __uint_as_float(u7 << 16); ay += __uint_as_float(u7 & 0xffff0000u);
        }
        if (j + 4 <= n) {
          int s0 = __builtin_amdgcn_readlane(idx, j);
          int s1 = __builtin_amdgcn_readlane(idx, j + 1);
          int s2 = __builtin_amdgcn_readlane(idx, j + 2);
          int s3 = __builtin_amdgcn_readlane(idx, j + 3);
          unsigned u0 = *(const unsigned*)(feat + (size_t)s0 * F + vcol);
          unsigned u1 = *(const unsigned*)(feat + (size_t)s1 * F + vcol);
          unsigned u2 = *(const unsigned*)(feat + (size_t)s2 * F + vcol);
          unsigned u3 = *(const unsigned*)(feat + (size_t)s3 * F + vcol);
          ax += __uint_as_float(u0 << 16); ay += __uint_as_float(u0 & 0xffff0000u);
          ax += __uint_as_float(u1 << 16); ay += __uint_as_float(u1 & 0xffff0000u);
          ax += __uint_as_float(u2 << 16); ay += __uint_as_float(u2 & 0xffff0000u);
          ax += __uint_as_float(u3 << 16); ay += __uint_as_float(u3 & 0xffff0000u);
          j += 4;
        }
        for (; j < n; ++j) {
          int s0 = __builtin_amdgcn_readlane(idx, j);
          unsigned u0 = *(const unsigned*)(feat + (size_t)s0 * F + vcol);
          ax += __uint_as_float(u0 << 16); ay += __uint_as_float(u0 & 0xffff0000u);
        }
        e += n;
      }
    }
    sT[r][lane * 2]     = ax;
    sT[r][lane * 2 + 1] = ay;
  }
  __syncthreads();

  // Phase B: GEMM. Thread tile = 4 rows x 4 cols. W from global (L1/L2-resident).
  const int cg = t & 31, rg = t >> 5;
  const int c = cg * 4;
  const float4 b4 = *(const float4*)(bias + c);
  float4 a0 = b4, a1 = b4, a2 = b4, a3 = b4;
  const float4* __restrict__ W4 = (const float4*)W;
#pragma unroll 8
  for (int d = 0; d < DF; ++d) {
    float4 w = W4[d * (DF / 4) + cg];
    float x0 = sT[rg * 4 + 0][d];
    float x1 = sT[rg * 4 + 1][d];
    float x2 = sT[rg * 4 + 2][d];
    float x3 = sT[rg * 4 + 3][d];
    a0.x = fmaf(x0, w.x, a0.x); a0.y = fmaf(x0, w.y, a0.y);
    a0.z = fmaf(x0, w.z, a0.z); a0.w = fmaf(x0, w.w, a0.w);
    a1.x = fmaf(x1, w.x, a1.x); a1.y = fmaf(x1, w.y, a1.y);
    a1.z = fmaf(x1, w.z, a1.z); a1.w = fmaf(x1, w.w, a1.w);
    a2.x = fmaf(x2, w.x, a2.x); a2.y = fmaf(x2, w.y, a2.y);
    a2.z = fmaf(x2, w.z, a2.z); a2.w = fmaf(x2, w.w, a2.w);
    a3.x = fmaf(x3, w.x, a3.x); a3.y = fmaf(x3, w.y, a3.y);
    a3.z = fmaf(x3, w.z, a3.z); a3.w = fmaf(x3, w.w, a3.w);
  }

  const int nodeb = row0 + rg * 4;
  if (OUT_BF16) {
    ushort* ob = (ushort*)outp;
    float4 r4[4] = {relu4(a0), relu4(a1), relu4(a2), relu4(a3)};
#pragma unroll
    for (int k = 0; k < 4; ++k) {
      if (nodeb + k < NN) {
        ushort4 u;
        u.x = f2bf(r4[k].x); u.y = f2bf(r4[k].y); u.z = f2bf(r4[k].z); u.w = f2bf(r4[k].w);
        *(ushort4*)(ob + (size_t)(nodeb + k) * F + v * DF + c) = u;
      }
    }
  } else {
    float* of = (float*)outp;
    if (nodeb + 0 < NN) *(float4*)(of + (size_t)(nodeb + 0) * F + v * DF + c) = relu4(a0);
    if (nodeb + 1 < NN) *(float4*)(of + (size_t)(nodeb + 1) * F + v * DF + c) = relu4(a1);
    if (nodeb + 2 < NN) *(float4*)(of + (size_t)(nodeb + 2) * F + v * DF + c) = relu4(a2);
    if (nodeb + 3 < NN) *(float4*)(of + (size_t)(nodeb + 3) * F + v * DF + c) = relu4(a3);
  }
}

// ---------------- launch ----------------

static inline size_t align_up(size_t x, size_t a) { return (x + a - 1) & ~(a - 1); }

extern "C" void kernel_launch(void* const* d_in, const int* in_sizes, int n_in,
                              void* d_out, int out_size, void* d_ws, size_t ws_size,
                              hipStream_t stream) {
  const float* h   = (const float*)d_in[0];
  const int*   src = (const int*)d_in[1];
  const int*   dst = (const int*)d_in[2];
  const float* W1  = (const float*)d_in[3];
  const float* b1  = (const float*)d_in[4];
  const float* W2  = (const float*)d_in[5];
  const float* b2  = (const float*)d_in[6];
  float* out = (float*)d_out;

  // Workspace layout
  char* ws = (char*)d_ws;
  size_t o = 0;
  int* deg  = (int*)(ws + o); o = align_up(o + (size_t)NN * 4, 1024);        // also reused as scatter cursor
  int* offs = (int*)(ws + o); o = align_up(o + (size_t)(NN + 1) * 4, 1024);
  int* bsum = (int*)(ws + o); o = align_up(o + 1024, 1024);
  int* csr  = (int*)(ws + o); o = align_up(o + (size_t)NE * 4, 1024);
  ushort* hb   = (ushort*)(ws + o); o = align_up(o + (size_t)NN * F * 2, 1024);  // bf16 h
  ushort* ybuf = (ushort*)(ws + o); o = align_up(o + (size_t)NN * F * 2, 1024);  // bf16 y
  (void)ws_size; (void)n_in; (void)in_sizes; (void)out_size;

  // CSR build + bf16 conversion (independent, same stream)
  hipMemsetAsync(deg, 0, (size_t)NN * 4, stream);
  k_count<<<1024, 256, 0, stream>>>(dst, deg);
  k_blocksum<<<NB, 256, 0, stream>>>(deg, bsum);
  k_scanb<<<1, 64, 0, stream>>>(bsum, NB, offs + NN);
  k_offsets<<<NB, 256, 0, stream>>>(deg, bsum, offs);
  hipMemsetAsync(deg, 0, (size_t)NN * 4, stream);  // reuse as per-node cursor
  k_scatter<<<1024, 256, 0, stream>>>(src, dst, offs, deg, csr);
  k_tobf16<<<2048, 256, 0, stream>>>(h, hb, NN * F / 4);

  // Two fused layers: layer1 per-view W1/b1 (bf16 out), layer2 shared W2/b2 (fp32 out)
  dim3 grid((NN + TR - 1) / TR, NV);
  k_layer<true ><<<grid, 256, 0, stream>>>(hb,   offs, csr, W1, b1, DF * DF, DF, ybuf);
  k_layer<false><<<grid, 256, 0, stream>>>(ybuf, offs, csr, W2, b2, 0,       0,  out);
}